// Round 10
// baseline (218.725 us; speedup 1.0000x reference)
//
#include <hip/hip_runtime.h>

// AdaptiveDecayMemory: out = ((Q K^T * scale) ∘ W_decay) V Wo^T * out_scale
// B=4, T=2048, D=1024.  bf16 MFMA, fp32 accum.
// gemmQ: 256x128 tile, BK=32, 4 waves of 128x64 (acc 8x4) -> 34.3 B/KFLOP
//   LDS traffic (r9's 64x64 waves were 45.8 B/KF = measured LDS port ceiling).
//   r9's proven pipeline: stage(t+1) at top, vmcnt(0)+barrier at bottom.
//   2x24KB LDS dbuf -> 2 blocks/CU co-resident.
//   BK=32 chunk swizzle: BOTH sides use chunk ^= (row&3) (r5's conflict bug
//   was a mismatched write-side involution).

using u16 = unsigned short;
typedef __bf16 bf16x8 __attribute__((ext_vector_type(8)));
typedef float f32x4 __attribute__((ext_vector_type(4)));

__device__ inline u16 f2bf(float f) {
  unsigned u = __builtin_bit_cast(unsigned, f);
  unsigned r = (u + 0x7FFFu + ((u >> 16) & 1u)) >> 16;   // RNE
  return (u16)r;
}

__device__ inline void gload16(const u16* g, u16* l) {
  __builtin_amdgcn_global_load_lds(
      (const __attribute__((address_space(1))) void*)g,
      (__attribute__((address_space(3))) void*)l, 16, 0, 0);
}

// ---------- merged prep: x cast + decay GEMV | weight casts ----------
__global__ __launch_bounds__(256) void prep(const float* __restrict__ x,
    u16* __restrict__ Xbf, const float* __restrict__ Wd,
    const float* __restrict__ bd, float* __restrict__ ldec,
    const float* __restrict__ Wq, const float* __restrict__ Wk,
    const float* __restrict__ Wv, const float* __restrict__ Wo,
    u16* __restrict__ Wall) {
  int b = blockIdx.x;
  int t = threadIdx.x;
  if (b < 8192) {
    float4 f = reinterpret_cast<const float4*>(x + (size_t)b * 1024)[t];
    float4 g = reinterpret_cast<const float4*>(Wd)[t];
    ushort4 o;
    o.x = f2bf(f.x); o.y = f2bf(f.y); o.z = f2bf(f.z); o.w = f2bf(f.w);
    reinterpret_cast<ushort4*>(Xbf + (size_t)b * 1024)[t] = o;
    float s = f.x * g.x + f.y * g.y + f.z * g.z + f.w * g.w;
    #pragma unroll
    for (int off = 32; off > 0; off >>= 1) s += __shfl_xor(s, off);
    __shared__ float red[4];
    if ((t & 63) == 0) red[t >> 6] = s;
    __syncthreads();
    if (t == 0) {
      float tot = red[0] + red[1] + red[2] + red[3];
      float dec = 1.f / (1.f + expf(-(tot + bd[0])));
      ldec[b] = logf(dec + 1e-8f);
    }
  } else {
    int wb = b - 8192;
    int m = wb >> 10;
    const float* src = (m == 0) ? Wq : (m == 1) ? Wk : (m == 2) ? Wv : Wo;
    int i = ((wb & 1023) * 256 + t) * 4;
    float4 f = *reinterpret_cast<const float4*>(src + i);
    ushort4 o;
    o.x = f2bf(f.x); o.y = f2bf(f.y); o.z = f2bf(f.z); o.w = f2bf(f.w);
    *reinterpret_cast<ushort4*>(Wall + (size_t)m * 1048576 + i) = o;
  }
}

// ---------- R partial merge: R[rows 0..1023/batch] = bf16(p0+p1) ----------
__global__ __launch_bounds__(256) void radd(const float* __restrict__ p0,
    const float* __restrict__ p1, u16* __restrict__ R) {
  size_t i = ((size_t)blockIdx.x * 256 + threadIdx.x) * 4;
  float4 a = *reinterpret_cast<const float4*>(p0 + i);
  float4 b = *reinterpret_cast<const float4*>(p1 + i);
  size_t batch = i >> 20, within = i & 1048575;
  ushort4 o;
  o.x = f2bf(a.x + b.x); o.y = f2bf(a.y + b.y);
  o.z = f2bf(a.z + b.z); o.w = f2bf(a.w + b.w);
  *reinterpret_cast<ushort4*>(R + batch * 2097152 + within) = o;
}

// ---------- gemmQ: 256x128, BK=32, 4 waves of 128x64, 2 blocks/CU ----------
// C[m,n] = sum_k A[m,k]*B[n,k]  (both K-contiguous).
// MODE 0: plain bf16.  MODE 1: S compact tri grid + decay epi -> bf16.
// MODE 2: R split-K (it<4 -> f32 partials, it>=4 -> bf16 direct).
// MODE 3: f32 * scale.
template <int MODE>
__global__ __launch_bounds__(256, 2)
void gemmQ(const u16* __restrict__ Ab, const u16* __restrict__ Bb,
           void* __restrict__ Cv, int lda, int ldb, int ldc, int K,
           int tiles_n, const float* __restrict__ ldec,
           const float* __restrict__ scale_ptr,
           float* __restrict__ aux0, float* __restrict__ aux1,
           long long abs_, long long bbs_, long long cbs_) {
  __shared__ __align__(16) u16 lds2[24576];   // 2 bufs x (A 256x32 | B 128x32) = 48 KiB

  const int batch = blockIdx.y;
  const u16* A = Ab + (size_t)batch * abs_;
  const u16* B = Bb + (size_t)batch * bbs_;

  const int bx = blockIdx.x;
  int it, jt, kt0, kend, ks = 0; bool part = false;
  if (MODE == 0 || MODE == 3) {
    it = bx / tiles_n; jt = bx % tiles_n; kt0 = 0; kend = K / 32;
  } else if (MODE == 1) {                      // S: 72 live tiles/batch, jt >= 2it
    int L = bx; it = 0;
    while (L >= 16 - 2 * it) { L -= 16 - 2 * it; ++it; }
    jt = 2 * it + L; kt0 = 0; kend = 32;
  } else {                                     // R: K=2048 -> 64 steps of 32
    if (bx < 64) {                             // it<4: split-K halves (f32 partials)
      it = bx >> 4; int rm = bx & 15; jt = rm >> 1; ks = rm & 1; part = true;
      kt0 = ks ? 32 : 8 * it; kend = ks ? 64 : 32;
    } else {
      int z = bx - 64; it = 4 + (z >> 3); jt = z & 7;
      kt0 = 8 * it; kend = 64;
    }
  }
  const int m0 = it * 256, n0 = jt * 128;

  const int tid = threadIdx.x;
  const int lane = tid & 63;
  const int w = tid >> 6;                      // 0..3
  const int wm = w >> 1, wn = w & 1;           // wave = 128x64 (2m x 2n)
  const int l15 = lane & 15, lhi = lane >> 4;
  const int rc = lhi;                          // frag k-chunk 0..3
  const int srow = lane >> 2;                  // staging row-within-16
  const int sch = (lane & 3) ^ ((lane >> 2) & 3);   // write-side involution

  const int span = kend - kt0;

  f32x4 acc[8][4];
  #pragma unroll
  for (int i = 0; i < 8; ++i)
    #pragma unroll
    for (int j = 0; j < 4; ++j) acc[i][j] = (f32x4)0.f;

  // stage one K-step: A 256x32 (16KB, 4 gloads) + B 128x32 (8KB, 2 gloads)
  auto stage = [&](int kt, int buf) {
    const size_t kb = (size_t)kt * 32 + sch * 8;
    u16* la = &lds2[buf * 12288];
    u16* lb = la + 8192;
    #pragma unroll
    for (int u = 0; u < 4; ++u)
      gload16(A + (size_t)(m0 + u * 64 + w * 16 + srow) * lda + kb,
              la + (u * 64 + w * 16) * 32);
    #pragma unroll
    for (int u = 0; u < 2; ++u)
      gload16(B + (size_t)(n0 + u * 64 + w * 16 + srow) * ldb + kb,
              lb + (u * 64 + w * 16) * 32);
  };

  stage(kt0, 0);
  asm volatile("s_waitcnt vmcnt(0)" ::: "memory");
  __builtin_amdgcn_s_barrier();

  for (int t = 0; t < span; ++t) {
    const int buf = t & 1;
    if (t + 1 < span) stage(kt0 + t + 1, buf ^ 1);   // issue early, land late

    const u16* baseA = &lds2[buf * 12288];
    const u16* baseB = baseA + 8192;
    bf16x8 af[8], bv[4];
    #pragma unroll
    for (int mi = 0; mi < 8; ++mi) {
      int r = wm * 128 + mi * 16 + l15;
      int c = rc ^ (r & 3);                    // read-side involution (matches sch)
      af[mi] = *reinterpret_cast<const bf16x8*>(&baseA[r * 32 + c * 8]);
    }
    #pragma unroll
    for (int ni = 0; ni < 4; ++ni) {
      int r = wn * 64 + ni * 16 + l15;
      int c = rc ^ (r & 3);
      bv[ni] = *reinterpret_cast<const bf16x8*>(&baseB[r * 32 + c * 8]);
    }

    __builtin_amdgcn_s_setprio(1);
    #pragma unroll
    for (int mi = 0; mi < 8; ++mi)
      #pragma unroll
      for (int ni = 0; ni < 4; ++ni)
        acc[mi][ni] = __builtin_amdgcn_mfma_f32_16x16x32_bf16(
            af[mi], bv[ni], acc[mi][ni], 0, 0, 0);
    __builtin_amdgcn_s_setprio(0);

    asm volatile("s_waitcnt vmcnt(0)" ::: "memory");  // t+1 landed (full-body cover)
    __builtin_amdgcn_s_barrier();
  }

  // epilogue: frag (mi,ni) -> row m0+wm*128+mi*16+lhi*4+q, col n0+wn*64+ni*16+l15
  if (MODE == 0) {
    u16* C = (u16*)Cv + (size_t)batch * cbs_;
    #pragma unroll
    for (int mi = 0; mi < 8; ++mi)
      #pragma unroll
      for (int q = 0; q < 4; ++q) {
        int row = m0 + wm * 128 + mi * 16 + lhi * 4 + q;
        u16* crow = C + (size_t)row * ldc + n0 + wn * 64 + l15;
        #pragma unroll
        for (int ni = 0; ni < 4; ++ni) crow[ni * 16] = f2bf(acc[mi][ni][q]);
      }
  } else if (MODE == 1) {
    u16* C = (u16*)Cv + (size_t)batch * cbs_;
    const float* ldp = ldec + (size_t)batch * 2048;
    float ldv[4];
    #pragma unroll
    for (int ni = 0; ni < 4; ++ni) ldv[ni] = ldp[n0 + wn * 64 + ni * 16 + l15];
    const float sc = 0.03125f;   // 1/sqrt(1024)
    #pragma unroll
    for (int mi = 0; mi < 8; ++mi)
      #pragma unroll
      for (int q = 0; q < 4; ++q) {
        int row = m0 + wm * 128 + mi * 16 + lhi * 4 + q;
        u16* crow = C + (size_t)row * ldc + n0 + wn * 64 + l15;
        #pragma unroll
        for (int ni = 0; ni < 4; ++ni) {
          int col = n0 + wn * 64 + ni * 16 + l15;
          int d = col - row;
          float wgt = (d > 0) ? expf(ldv[ni] * (float)(d - 1)) : 0.f;
          crow[ni * 16] = f2bf(acc[mi][ni][q] * sc * wgt);
        }
      }
  } else if (MODE == 2) {
    if (part) {
      float* P = (ks ? aux1 : aux0) + (size_t)batch * 1048576;
      #pragma unroll
      for (int mi = 0; mi < 8; ++mi)
        #pragma unroll
        for (int q = 0; q < 4; ++q) {
          int row = m0 + wm * 128 + mi * 16 + lhi * 4 + q;   // < 1024
          float* crow = P + (size_t)row * 1024 + n0 + wn * 64 + l15;
          #pragma unroll
          for (int ni = 0; ni < 4; ++ni) crow[ni * 16] = acc[mi][ni][q];
        }
    } else {
      u16* C = (u16*)Cv + (size_t)batch * cbs_;
      #pragma unroll
      for (int mi = 0; mi < 8; ++mi)
        #pragma unroll
        for (int q = 0; q < 4; ++q) {
          int row = m0 + wm * 128 + mi * 16 + lhi * 4 + q;
          u16* crow = C + (size_t)row * ldc + n0 + wn * 64 + l15;
          #pragma unroll
          for (int ni = 0; ni < 4; ++ni) crow[ni * 16] = f2bf(acc[mi][ni][q]);
        }
    }
  } else {
    float* C = (float*)Cv + (size_t)batch * cbs_;
    const float sc = scale_ptr[0];
    #pragma unroll
    for (int mi = 0; mi < 8; ++mi)
      #pragma unroll
      for (int q = 0; q < 4; ++q) {
        int row = m0 + wm * 128 + mi * 16 + lhi * 4 + q;
        float* crow = C + (size_t)row * ldc + n0 + wn * 64 + l15;
        #pragma unroll
        for (int ni = 0; ni < 4; ++ni) crow[ni * 16] = acc[mi][ni][q] * sc;
      }
  }
}

extern "C" void kernel_launch(void* const* d_in, const int* in_sizes, int n_in,
                              void* d_out, int out_size, void* d_ws, size_t ws_size,
                              hipStream_t stream) {
  const float* x   = (const float*)d_in[0];
  const float* Wq  = (const float*)d_in[1];
  const float* Wk  = (const float*)d_in[2];
  const float* Wv  = (const float*)d_in[3];
  const float* Wo  = (const float*)d_in[4];
  const float* Wd  = (const float*)d_in[5];
  const float* bd  = (const float*)d_in[6];
  const float* osc = (const float*)d_in[7];
  float* out = (float*)d_out;

  char* ws = (char*)d_ws;
  size_t off = 0;
  u16* Xbf  = (u16*)(ws + off); off += (size_t)8192 * 1024 * 2;
  u16* Wall = (u16*)(ws + off); off += (size_t)4096 * 1024 * 2;
  u16* VT   = (u16*)(ws + off); off += (size_t)1024 * 8192 * 2;
  u16* S    = (u16*)(ws + off); off += (size_t)4 * 2048 * 2048 * 2;
  float* ldec = (float*)(ws + off); off += (size_t)8192 * 4;
  u16* QK   = (u16*)(ws + off); off += (size_t)8192 * 2048 * 2;
  u16* R    = QK;                               // alias: QK dead once S built
  float* Rp0 = (float*)Xbf;                     // alias: Xbf dead after QK+VT
  float* Rp1 = (float*)((char*)QK + 16777216);  // 2nd half of QK region

  u16* Wqk = Wall;
  u16* Wvb = Wall + 2 * 1048576;
  u16* Wob = Wall + 3 * 1048576;

  // 1) merged prep
  prep<<<12288, 256, 0, stream>>>(x, Xbf, Wd, bd, ldec, Wq, Wk, Wv, Wo, Wall);

  // 2) QK = Xbf @ Wqk^T  [8192 x 2048]  (512 blocks, 2/CU)
  gemmQ<0><<<dim3(32 * 16, 1), 256, 0, stream>>>(
      Xbf, Wqk, QK, 1024, 1024, 2048, 1024, 16, nullptr, nullptr, nullptr, nullptr,
      0, 0, 0);

  // 3) VT = Wvb @ Xbf^T  [1024 x 8192]  (256 blocks)
  gemmQ<0><<<dim3(4 * 64, 1), 256, 0, stream>>>(
      Wvb, Xbf, VT, 1024, 1024, 8192, 1024, 64, nullptr, nullptr, nullptr, nullptr,
      0, 0, 0);

  // 4) S_b = (Q_b K_b^T /32) ∘ weights -> bf16, compact tri (72 x 4 blocks)
  gemmQ<1><<<dim3(72, 4), 256, 0, stream>>>(
      QK, QK + 1024, S, 2048, 2048, 2048, 1024, 0, ldec, nullptr, nullptr, nullptr,
      4194304LL, 4194304LL, 4194304LL);

  // 5) R_b = S_b @ V_b, split-K for it<4 (96 x 4 blocks), max 32 steps/block
  gemmQ<2><<<dim3(96, 4), 256, 0, stream>>>(
      S, VT, R, 2048, 8192, 1024, 2048, 0, nullptr, nullptr, Rp0, Rp1,
      4194304LL, 2048LL, 2097152LL);

  // 5b) merge partials (rows 0..1023 per batch)
  radd<<<4096, 256, 0, stream>>>(Rp0, Rp1, R);

  // 6) out = R @ Wo^T * out_scale  [8192 x 1024] fp32  (256 blocks)
  gemmQ<3><<<dim3(32 * 8, 1), 256, 0, stream>>>(
      R, Wob, out, 1024, 1024, 1024, 1024, 8, nullptr, osc, nullptr, nullptr,
      0, 0, 0);
}